// Round 1
// baseline (7663.393 us; speedup 1.0000x reference)
//
#include <hip/hip_runtime.h>
#include <math.h>

#define BB 256
#define NN 1023
#define FF 8
#define HH 256
#define LL 512
#define DEPTH 9

enum { EPI_NONE = 0, EPI_SIGMUL = 1, EPI_RELU = 2 };

// C[M x Nc] = A[M x K] (row stride lda) * W[Nc x K]^T + bias, with epilogue.
// Tiles 64x64, K-step 16, 256 threads, 4x4 micro-tile per thread.
template <int EPI>
__global__ __launch_bounds__(256) void gemm_epi(
    const float* __restrict__ A, int lda,
    const float* __restrict__ W,     // Nc x K row-major
    const float* __restrict__ bias,  // Nc
    const float* __restrict__ aux, int ldaux,  // for SIGMUL epilogue
    float* __restrict__ C, int ldc,
    int M, int Nc, int K)
{
    __shared__ float As[16 * 68];
    __shared__ float Ws[16 * 68];
    const int tid = threadIdx.x;
    const int tx = tid & 15;   // output col group
    const int ty = tid >> 4;   // output row group
    const int bm0 = blockIdx.y * 64;
    const int bn0 = blockIdx.x * 64;

    float acc[4][4] = {};

    for (int kk = 0; kk < K; kk += 16) {
        // Load tiles: thread -> (k = tid&15, r = tid>>4), 4 row-passes.
        const int k = tid & 15;
        const int r = tid >> 4;
#pragma unroll
        for (int p = 0; p < 4; ++p) {
            As[k * 68 + (r + p * 16)] = A[(size_t)(bm0 + r + p * 16) * lda + kk + k];
            Ws[k * 68 + (r + p * 16)] = W[(size_t)(bn0 + r + p * 16) * K + kk + k];
        }
        __syncthreads();
#pragma unroll
        for (int k2 = 0; k2 < 16; ++k2) {
            float4 a4 = *(const float4*)&As[k2 * 68 + 4 * ty];
            float4 w4 = *(const float4*)&Ws[k2 * 68 + 4 * tx];
            float av[4] = {a4.x, a4.y, a4.z, a4.w};
            float wv[4] = {w4.x, w4.y, w4.z, w4.w};
#pragma unroll
            for (int i = 0; i < 4; ++i)
#pragma unroll
                for (int j = 0; j < 4; ++j)
                    acc[i][j] += av[i] * wv[j];
        }
        __syncthreads();
    }

#pragma unroll
    for (int i = 0; i < 4; ++i) {
        const int gr = bm0 + 4 * ty + i;
#pragma unroll
        for (int j = 0; j < 4; ++j) {
            const int gc = bn0 + 4 * tx + j;
            float v = acc[i][j] + bias[gc];
            if (EPI == EPI_SIGMUL) {
                float s = 1.0f / (1.0f + __expf(-v));
                v = s * aux[(size_t)gr * ldaux + gc];
            } else if (EPI == EPI_RELU) {
                v = fmaxf(v, 0.0f);
            }
            C[(size_t)gr * ldc + gc] = v;
        }
    }
}

// Leaves: h0[b*512+j, h] = dot(data[b, 511+j, :], Wu[h,:]) + bu[h]
__global__ __launch_bounds__(256) void leaves_kernel(
    const float* __restrict__ data, const float* __restrict__ Wu,
    const float* __restrict__ bu, float* __restrict__ h0)
{
    const int i = blockIdx.x;  // b*512 + j
    const int h = threadIdx.x;
    const int b = i >> 9;
    const int j = i & 511;
    const float* d = data + ((size_t)b * NN + (LL - 1) + j) * FF;
    float acc = bu[h];
#pragma unroll
    for (int f = 0; f < FF; ++f) acc += d[f] * Wu[h * FF + f];
    h0[(size_t)i * HH + h] = acc;
}

// Build hhhu cols 256..1024 = [parent_u, h_l, h_r] for chunk rows [r0, r0+R)
__global__ __launch_bounds__(256) void build_hhu(
    const float* __restrict__ data, const float* __restrict__ Wu,
    const float* __restrict__ bu, const float* __restrict__ hprev,
    float* __restrict__ hhhu, int l, int r0)
{
    const int n = 1 << l;
    const int i = r0 + blockIdx.x;  // global row = b*n + m
    const int h = threadIdx.x;
    const int b = i >> l;
    const int m = i & (n - 1);

    const float* d = data + ((size_t)b * NN + (n - 1) + m) * FF;
    float acc = bu[h];
#pragma unroll
    for (int f = 0; f < FF; ++f) acc += d[f] * Wu[h * FF + f];

    float* row = hhhu + (size_t)blockIdx.x * 1024;
    row[256 + h] = acc;
    row[512 + h] = hprev[((size_t)b * (2 * n) + 2 * m) * HH + h];
    row[768 + h] = hprev[((size_t)b * (2 * n) + 2 * m + 1) * HH + h];
}

// Softmax over 4 groups + gated combine -> h_next
__global__ __launch_bounds__(256) void combine_kernel(
    const float* __restrict__ zlin, const float* __restrict__ hhhu,
    float* __restrict__ hnext, int r0)
{
    const int i = blockIdx.x;
    const int c = threadIdx.x;
    const float* zl = zlin + (size_t)i * 1024;
    const float* hr = hhhu + (size_t)i * 1024;
    float z0 = zl[c], z1 = zl[c + 256], z2 = zl[c + 512], z3 = zl[c + 768];
    float mx = fmaxf(fmaxf(z0, z1), fmaxf(z2, z3));
    float e0 = __expf(z0 - mx), e1 = __expf(z1 - mx);
    float e2 = __expf(z2 - mx), e3 = __expf(z3 - mx);
    float s = e0 + e1 + e2 + e3;
    hnext[(size_t)(r0 + i) * HH + c] =
        (e0 * hr[c] + e1 * hr[c + 256] + e2 * hr[c + 512] + e3 * hr[c + 768]) / s;
}

__global__ __launch_bounds__(256) void final_kernel(
    const float* __restrict__ hfin, const float* __restrict__ Wp,
    const float* __restrict__ bp, float* __restrict__ out)
{
    const int b = blockIdx.x;
    const int t = threadIdx.x;
    __shared__ float red[256];
    red[t] = hfin[(size_t)b * HH + t] * Wp[t];
    __syncthreads();
    for (int s = 128; s > 0; s >>= 1) {
        if (t < s) red[t] += red[t + s];
        __syncthreads();
    }
    if (t == 0) out[b] = red[0] + bp[0];
}

extern "C" void kernel_launch(void* const* d_in, const int* in_sizes, int n_in,
                              void* d_out, int out_size, void* d_ws, size_t ws_size,
                              hipStream_t stream)
{
    const float* data = (const float*)d_in[0];
    const float* Wu = (const float*)d_in[1];
    const float* bu = (const float*)d_in[2];
    const float* Wr = (const float*)d_in[3];
    const float* br = (const float*)d_in[4];
    const float* Wh = (const float*)d_in[5];
    const float* bh = (const float*)d_in[6];
    const float* Wz = (const float*)d_in[7];
    const float* bz = (const float*)d_in[8];
    const float* Wp = (const float*)d_in[9];
    const float* bp = (const float*)d_in[10];
    float* out = (float*)d_out;

    float* ws = (float*)d_ws;
    const size_t CAP = 8192;  // rows per chunk
    float* hA = ws;                              // B*512*H = 33.5M floats
    float* hB = hA + (size_t)BB * 512 * HH;      // B*256*H = 16.8M floats
    float* hhhu = hB + (size_t)BB * 256 * HH;    // CAP*1024
    float* zbuf = hhhu + CAP * 1024;             // CAP*1024 (rh then zlin)

    leaves_kernel<<<BB * 512, 256, 0, stream>>>(data, Wu, bu, hA);

    float* hprev = hA;
    float* hnext = hB;
    for (int l = DEPTH - 1; l >= 0; --l) {
        const size_t M = (size_t)BB << l;
        for (size_t r0 = 0; r0 < M; r0 += CAP) {
            const int R = (int)((M - r0 < CAP) ? (M - r0) : CAP);
            build_hhu<<<R, 256, 0, stream>>>(data, Wu, bu, hprev, hhhu, l, (int)r0);
            dim3 g1(768 / 64, R / 64);
            gemm_epi<EPI_SIGMUL><<<g1, 256, 0, stream>>>(
                hhhu + 256, 1024, Wr, br, hhhu + 256, 1024, zbuf, 1024, R, 768, 768);
            dim3 g2(256 / 64, R / 64);
            gemm_epi<EPI_RELU><<<g2, 256, 0, stream>>>(
                zbuf, 1024, Wh, bh, nullptr, 0, hhhu, 1024, R, 256, 768);
            dim3 g3(1024 / 64, R / 64);
            gemm_epi<EPI_NONE><<<g3, 256, 0, stream>>>(
                hhhu, 1024, Wz, bz, nullptr, 0, zbuf, 1024, R, 1024, 1024);
            combine_kernel<<<R, 256, 0, stream>>>(zbuf, hhhu, hnext, (int)r0);
        }
        float* t = hprev; hprev = hnext; hnext = t;
    }
    final_kernel<<<BB, 256, 0, stream>>>(hprev, Wp, bp, out);
}

// Round 2
// 1638.093 us; speedup vs baseline: 4.6782x; 4.6782x over previous
//
#include <hip/hip_runtime.h>
#include <math.h>

#define BB 256
#define NN 1023
#define FF 8
#define HH 256
#define LL 512
#define DEPTH 9

enum { EPI_NONE = 0, EPI_SIGMUL = 1, EPI_RELU = 2 };

typedef __bf16 bf16x8_t __attribute__((ext_vector_type(8)));
typedef float f32x4_t __attribute__((ext_vector_type(4)));

__device__ __forceinline__ void stage16(const void* g, void* l) {
    __builtin_amdgcn_global_load_lds(
        (const __attribute__((address_space(1))) void*)g,
        (__attribute__((address_space(3))) void*)l,
        16, 0, 0);
}

// C[M x Nc] = A[M x K](bf16) * W[Nc x K](bf16)^T + bias, fused epilogue.
// 128x128 tile, BK=32, 4 waves, mfma_f32_16x16x32_bf16, 4x4 frags/wave.
template <int EPI>
__global__ __launch_bounds__(256) void gemm_mfma(
    const __bf16* __restrict__ A, int lda,
    const __bf16* __restrict__ W,       // Nc x K row-major (== B^T)
    const float* __restrict__ bias,     // Nc
    const __bf16* __restrict__ aux, int ldaux,  // SIGMUL epilogue
    void* __restrict__ Cout, int ldc,
    int K)
{
    __shared__ __bf16 As[128 * 32];
    __shared__ __bf16 Bs[128 * 32];
    const int tid = threadIdx.x;
    const int lane = tid & 63;
    const int w = tid >> 6;
    const int wr = w >> 1, wc = w & 1;
    const int bm0 = blockIdx.y * 128;
    const int bn0 = blockIdx.x * 128;

    const int srow = lane >> 2;        // 0..15 within a 16-row segment
    const int scol = (lane & 3) * 8;   // bf16 col within 32

    f32x4_t acc[4][4];
#pragma unroll
    for (int i = 0; i < 4; ++i)
#pragma unroll
        for (int j = 0; j < 4; ++j) acc[i][j] = (f32x4_t){0.f, 0.f, 0.f, 0.f};

    const int rA = lane & 15;
    const int kslot = (lane >> 4) * 8;

    for (int kk = 0; kk < K; kk += 32) {
        // stage A,B tiles: each wave fills rows [w*16, w*16+16) and [64+w*16, ...)
        stage16(A + (size_t)(bm0 + w * 16 + srow) * lda + kk + scol,
                &As[(w * 16) * 32]);
        stage16(A + (size_t)(bm0 + 64 + w * 16 + srow) * lda + kk + scol,
                &As[(64 + w * 16) * 32]);
        stage16(W + (size_t)(bn0 + w * 16 + srow) * K + kk + scol,
                &Bs[(w * 16) * 32]);
        stage16(W + (size_t)(bn0 + 64 + w * 16 + srow) * K + kk + scol,
                &Bs[(64 + w * 16) * 32]);
        __syncthreads();

        bf16x8_t af[4], bfr[4];
#pragma unroll
        for (int i = 0; i < 4; ++i)
            af[i] = *(const bf16x8_t*)&As[(wr * 64 + i * 16 + rA) * 32 + kslot];
#pragma unroll
        for (int j = 0; j < 4; ++j)
            bfr[j] = *(const bf16x8_t*)&Bs[(wc * 64 + j * 16 + rA) * 32 + kslot];
#pragma unroll
        for (int i = 0; i < 4; ++i)
#pragma unroll
            for (int j = 0; j < 4; ++j)
                acc[i][j] = __builtin_amdgcn_mfma_f32_16x16x32_bf16(
                    af[i], bfr[j], acc[i][j], 0, 0, 0);
        __syncthreads();
    }

    const int rowbase = bm0 + wr * 64;
    const int colbase = bn0 + wc * 64;
#pragma unroll
    for (int j = 0; j < 4; ++j) {
        const int gc = colbase + j * 16 + (lane & 15);
        const float bv = bias[gc];
#pragma unroll
        for (int i = 0; i < 4; ++i) {
#pragma unroll
            for (int reg = 0; reg < 4; ++reg) {
                const int gr = rowbase + i * 16 + (lane >> 4) * 4 + reg;
                float v = acc[i][j][reg] + bv;
                if (EPI == EPI_SIGMUL) {
                    float s = 1.0f / (1.0f + __expf(-v));
                    v = s * (float)aux[(size_t)gr * ldaux + gc];
                    ((__bf16*)Cout)[(size_t)gr * ldc + gc] = (__bf16)v;
                } else if (EPI == EPI_RELU) {
                    v = fmaxf(v, 0.0f);
                    ((__bf16*)Cout)[(size_t)gr * ldc + gc] = (__bf16)v;
                } else {
                    ((float*)Cout)[(size_t)gr * ldc + gc] = v;
                }
            }
        }
    }
}

__global__ __launch_bounds__(256) void convert_weights(
    const float* __restrict__ Wr, const float* __restrict__ Wh,
    const float* __restrict__ Wz, __bf16* __restrict__ Wrb,
    __bf16* __restrict__ Whb, __bf16* __restrict__ Wzb)
{
    const int NR = 768 * 768, NH = 256 * 768, NZ = 1024 * 1024;
    for (int i = blockIdx.x * 256 + threadIdx.x; i < NR + NH + NZ;
         i += gridDim.x * 256) {
        if (i < NR) Wrb[i] = (__bf16)Wr[i];
        else if (i < NR + NH) Whb[i - NR] = (__bf16)Wh[i - NR];
        else Wzb[i - NR - NH] = (__bf16)Wz[i - NR - NH];
    }
}

__global__ __launch_bounds__(256) void leaves_kernel(
    const float* __restrict__ data, const float* __restrict__ Wu,
    const float* __restrict__ bu, __bf16* __restrict__ h0)
{
    const int i = blockIdx.x;  // b*512 + j
    const int h = threadIdx.x;
    const int b = i >> 9;
    const int j = i & 511;
    const float* d = data + ((size_t)b * NN + (LL - 1) + j) * FF;
    float acc = bu[h];
#pragma unroll
    for (int f = 0; f < FF; ++f) acc += d[f] * Wu[h * FF + f];
    h0[(size_t)i * HH + h] = (__bf16)acc;
}

// hhhu cols 256..1024 = [parent_u, h_l, h_r] for chunk rows [r0, r0+R)
__global__ __launch_bounds__(256) void build_hhu(
    const float* __restrict__ data, const float* __restrict__ Wu,
    const float* __restrict__ bu, const __bf16* __restrict__ hprev,
    __bf16* __restrict__ hhhu, int l, int r0)
{
    const int n = 1 << l;
    const int i = r0 + blockIdx.x;  // global row = b*n + m
    const int h = threadIdx.x;
    const int b = i >> l;
    const int m = i & (n - 1);

    const float* d = data + ((size_t)b * NN + (n - 1) + m) * FF;
    float acc = bu[h];
#pragma unroll
    for (int f = 0; f < FF; ++f) acc += d[f] * Wu[h * FF + f];

    __bf16* row = hhhu + (size_t)blockIdx.x * 1024;
    row[256 + h] = (__bf16)acc;
    row[512 + h] = hprev[((size_t)b * (2 * n) + 2 * m) * HH + h];
    row[768 + h] = hprev[((size_t)b * (2 * n) + 2 * m + 1) * HH + h];
}

__global__ __launch_bounds__(256) void combine_kernel(
    const float* __restrict__ zlin, const __bf16* __restrict__ hhhu,
    __bf16* __restrict__ hnext, int r0)
{
    const int i = blockIdx.x;
    const int c = threadIdx.x;
    const float* zl = zlin + (size_t)i * 1024;
    const __bf16* hr = hhhu + (size_t)i * 1024;
    float z0 = zl[c], z1 = zl[c + 256], z2 = zl[c + 512], z3 = zl[c + 768];
    float mx = fmaxf(fmaxf(z0, z1), fmaxf(z2, z3));
    float e0 = __expf(z0 - mx), e1 = __expf(z1 - mx);
    float e2 = __expf(z2 - mx), e3 = __expf(z3 - mx);
    float s = e0 + e1 + e2 + e3;
    float v = (e0 * (float)hr[c] + e1 * (float)hr[c + 256] +
               e2 * (float)hr[c + 512] + e3 * (float)hr[c + 768]) / s;
    hnext[(size_t)(r0 + i) * HH + c] = (__bf16)v;
}

__global__ __launch_bounds__(256) void final_kernel(
    const __bf16* __restrict__ hfin, const float* __restrict__ Wp,
    const float* __restrict__ bp, float* __restrict__ out)
{
    const int b = blockIdx.x;
    const int t = threadIdx.x;
    __shared__ float red[256];
    red[t] = (float)hfin[(size_t)b * HH + t] * Wp[t];
    __syncthreads();
    for (int s = 128; s > 0; s >>= 1) {
        if (t < s) red[t] += red[t + s];
        __syncthreads();
    }
    if (t == 0) out[b] = red[0] + bp[0];
}

extern "C" void kernel_launch(void* const* d_in, const int* in_sizes, int n_in,
                              void* d_out, int out_size, void* d_ws, size_t ws_size,
                              hipStream_t stream)
{
    const float* data = (const float*)d_in[0];
    const float* Wu = (const float*)d_in[1];
    const float* bu = (const float*)d_in[2];
    const float* Wr = (const float*)d_in[3];
    const float* br = (const float*)d_in[4];
    const float* Wh = (const float*)d_in[5];
    const float* bh = (const float*)d_in[6];
    const float* Wz = (const float*)d_in[7];
    const float* bz = (const float*)d_in[8];
    const float* Wp = (const float*)d_in[9];
    const float* bp = (const float*)d_in[10];
    float* out = (float*)d_out;

    const size_t CAP = 16384;  // rows per chunk (multiple of 128)
    char* w = (char*)d_ws;
    __bf16* hA = (__bf16*)w;  w += (size_t)BB * 512 * HH * 2;   // 67.1 MB
    __bf16* hB = (__bf16*)w;  w += (size_t)BB * 256 * HH * 2;   // 33.6 MB
    __bf16* hhhu = (__bf16*)w; w += CAP * 1024 * 2;             // 33.6 MB
    __bf16* rh = (__bf16*)w;   w += CAP * 768 * 2;              // 25.2 MB
    float* zlin = (float*)w;   w += CAP * 1024 * 4;             // 67.1 MB
    __bf16* Wrb = (__bf16*)w;  w += (size_t)768 * 768 * 2;
    __bf16* Whb = (__bf16*)w;  w += (size_t)256 * 768 * 2;
    __bf16* Wzb = (__bf16*)w;  w += (size_t)1024 * 1024 * 2;

    convert_weights<<<2048, 256, 0, stream>>>(Wr, Wh, Wz, Wrb, Whb, Wzb);
    leaves_kernel<<<BB * 512, 256, 0, stream>>>(data, Wu, bu, hA);

    __bf16* hprev = hA;
    __bf16* hnext = hB;
    for (int l = DEPTH - 1; l >= 0; --l) {
        const size_t M = (size_t)BB << l;
        for (size_t r0 = 0; r0 < M; r0 += CAP) {
            const int R = (int)((M - r0 < CAP) ? (M - r0) : CAP);
            build_hhu<<<R, 256, 0, stream>>>(data, Wu, bu, hprev, hhhu, l, (int)r0);
            dim3 g1(768 / 128, R / 128);
            gemm_mfma<EPI_SIGMUL><<<g1, 256, 0, stream>>>(
                hhhu + 256, 1024, Wrb, br, hhhu + 256, 1024, rh, 768, 768);
            dim3 g2(256 / 128, R / 128);
            gemm_mfma<EPI_RELU><<<g2, 256, 0, stream>>>(
                rh, 768, Whb, bh, nullptr, 0, hhhu, 1024, 768);
            dim3 g3(1024 / 128, R / 128);
            gemm_mfma<EPI_NONE><<<g3, 256, 0, stream>>>(
                hhhu, 1024, Wzb, bz, nullptr, 0, zlin, 1024, 1024);
            combine_kernel<<<R, 256, 0, stream>>>(zlin, hhhu, hnext, (int)r0);
        }
        __bf16* t = hprev; hprev = hnext; hnext = t;
    }
    final_kernel<<<BB, 256, 0, stream>>>(hprev, Wp, bp, out);
}

// Round 3
// 1396.574 us; speedup vs baseline: 5.4873x; 1.1729x over previous
//
#include <hip/hip_runtime.h>
#include <math.h>

#define BB 256
#define NN 1023
#define FF 8
#define HH 256
#define DEPTH 9

enum { EPI_NONE = 0, EPI_SIGMUL = 1, EPI_RELU = 2, EPI_COMBINE = 3 };

typedef __bf16 bf16x8_t __attribute__((ext_vector_type(8)));
typedef __bf16 bf16x4_t __attribute__((ext_vector_type(4)));
typedef float f32x4_t __attribute__((ext_vector_type(4)));

__device__ __forceinline__ void stage16(const void* g, void* l) {
    __builtin_amdgcn_global_load_lds(
        (const __attribute__((address_space(1))) void*)g,
        (__attribute__((address_space(3))) void*)l,
        16, 0, 0);
}

// C[M x Nc] = A[M x K](bf16) * W[Nc x K](bf16)^T + bias, fused epilogue.
// 128x128 tile, BK=32, 4 waves, mfma_f32_16x16x32_bf16, 4x4 frags/wave.
// EPI_COMBINE: W rows are PRE-PERMUTED so the 4 softmax-group members of
// output group G sit in one wave's 4 j-fragments at the same lane; the
// epilogue does fp32 softmax-of-4 + gated sum over aux (hhhu) and writes
// h_next (bf16, ldc=HH) directly.
template <int EPI>
__global__ __launch_bounds__(256) void gemm_mfma(
    const __bf16* __restrict__ A, int lda,
    const __bf16* __restrict__ W,       // Nc x K row-major (== B^T)
    const float* __restrict__ bias,     // Nc (permuted for COMBINE)
    const __bf16* __restrict__ aux, int ldaux,
    void* __restrict__ Cout, int ldc,
    int K)
{
    __shared__ __bf16 As[128 * 32];
    __shared__ __bf16 Bs[128 * 32];
    const int tid = threadIdx.x;
    const int lane = tid & 63;
    const int w = tid >> 6;
    const int wr = w >> 1, wc = w & 1;

    // Bijective XCD-aware swizzle (m204): consecutive logical blocks
    // (which share the A row-panel) land on the same XCD's L2.
    const int nwg = gridDim.x * gridDim.y;
    const int hw = blockIdx.y * gridDim.x + blockIdx.x;
    const int xcd = hw & 7, k0 = hw >> 3;
    const int qq = nwg >> 3, rr = nwg & 7;
    const int wg = (xcd < rr ? xcd * (qq + 1) : rr * (qq + 1) + (xcd - rr) * qq) + k0;
    const int bm0 = (wg / gridDim.x) * 128;
    const int bn0 = (wg % gridDim.x) * 128;

    const int srow = lane >> 2;        // 0..15 within a 16-row segment
    const int scol = (lane & 3) * 8;   // bf16 col within 32

    f32x4_t acc[4][4];
#pragma unroll
    for (int i = 0; i < 4; ++i)
#pragma unroll
        for (int j = 0; j < 4; ++j) acc[i][j] = (f32x4_t){0.f, 0.f, 0.f, 0.f};

    const int rA = lane & 15;
    const int kslot = (lane >> 4) * 8;

    for (int kk = 0; kk < K; kk += 32) {
        stage16(A + (size_t)(bm0 + w * 16 + srow) * lda + kk + scol,
                &As[(w * 16) * 32]);
        stage16(A + (size_t)(bm0 + 64 + w * 16 + srow) * lda + kk + scol,
                &As[(64 + w * 16) * 32]);
        stage16(W + (size_t)(bn0 + w * 16 + srow) * K + kk + scol,
                &Bs[(w * 16) * 32]);
        stage16(W + (size_t)(bn0 + 64 + w * 16 + srow) * K + kk + scol,
                &Bs[(64 + w * 16) * 32]);
        __syncthreads();

        bf16x8_t af[4], bfr[4];
#pragma unroll
        for (int i = 0; i < 4; ++i)
            af[i] = *(const bf16x8_t*)&As[(wr * 64 + i * 16 + rA) * 32 + kslot];
#pragma unroll
        for (int j = 0; j < 4; ++j)
            bfr[j] = *(const bf16x8_t*)&Bs[(wc * 64 + j * 16 + rA) * 32 + kslot];
#pragma unroll
        for (int i = 0; i < 4; ++i)
#pragma unroll
            for (int j = 0; j < 4; ++j)
                acc[i][j] = __builtin_amdgcn_mfma_f32_16x16x32_bf16(
                    af[i], bfr[j], acc[i][j], 0, 0, 0);
        __syncthreads();
    }

    if (EPI == EPI_COMBINE) {
        const int r = lane & 15;
        const int G = ((bn0 + wc * 64) >> 2) + r;   // output h column
        float bz4[4];
#pragma unroll
        for (int g = 0; g < 4; ++g) bz4[g] = bias[bn0 + wc * 64 + g * 16 + r];
#pragma unroll
        for (int i = 0; i < 4; ++i) {
#pragma unroll
            for (int reg = 0; reg < 4; ++reg) {
                const int gr = bm0 + wr * 64 + i * 16 + (lane >> 4) * 4 + reg;
                float z0 = acc[i][0][reg] + bz4[0];
                float z1 = acc[i][1][reg] + bz4[1];
                float z2 = acc[i][2][reg] + bz4[2];
                float z3 = acc[i][3][reg] + bz4[3];
                float mx = fmaxf(fmaxf(z0, z1), fmaxf(z2, z3));
                float e0 = __expf(z0 - mx), e1 = __expf(z1 - mx);
                float e2 = __expf(z2 - mx), e3 = __expf(z3 - mx);
                const __bf16* hrow = aux + (size_t)gr * ldaux + G;
                float hv = (e0 * (float)hrow[0] + e1 * (float)hrow[256] +
                            e2 * (float)hrow[512] + e3 * (float)hrow[768]) /
                           (e0 + e1 + e2 + e3);
                ((__bf16*)Cout)[(size_t)gr * ldc + G] = (__bf16)hv;
            }
        }
    } else {
        const int rowbase = bm0 + wr * 64;
        const int colbase = bn0 + wc * 64;
#pragma unroll
        for (int j = 0; j < 4; ++j) {
            const int gc = colbase + j * 16 + (lane & 15);
            const float bv = bias[gc];
#pragma unroll
            for (int i = 0; i < 4; ++i) {
#pragma unroll
                for (int reg = 0; reg < 4; ++reg) {
                    const int gr = rowbase + i * 16 + (lane >> 4) * 4 + reg;
                    float v = acc[i][j][reg] + bv;
                    if (EPI == EPI_SIGMUL) {
                        float s = 1.0f / (1.0f + __expf(-v));
                        v = s * (float)aux[(size_t)gr * ldaux + gc];
                        ((__bf16*)Cout)[(size_t)gr * ldc + gc] = (__bf16)v;
                    } else if (EPI == EPI_RELU) {
                        v = fmaxf(v, 0.0f);
                        ((__bf16*)Cout)[(size_t)gr * ldc + gc] = (__bf16)v;
                    } else {
                        ((float*)Cout)[(size_t)gr * ldc + gc] = v;
                    }
                }
            }
        }
    }
}

// Wr/Wh -> bf16; Wz -> bf16 with softmax-group row permutation:
// permuted row p holds original row o = ((p>>4)&3)*256 + (p>>6)*16 + (p&15).
__global__ __launch_bounds__(256) void convert_weights(
    const float* __restrict__ Wr, const float* __restrict__ Wh,
    const float* __restrict__ Wz, const float* __restrict__ bz,
    __bf16* __restrict__ Wrb, __bf16* __restrict__ Whb,
    __bf16* __restrict__ Wzb, float* __restrict__ bzp)
{
    const int NR = 768 * 768, NH2 = 256 * 768, NZ = 1024 * 1024;
    const int idx0 = blockIdx.x * 256 + threadIdx.x;
    for (int i = idx0; i < NR + NH2 + NZ; i += gridDim.x * 256) {
        if (i < NR) Wrb[i] = (__bf16)Wr[i];
        else if (i < NR + NH2) Whb[i - NR] = (__bf16)Wh[i - NR];
        else {
            const int z = i - NR - NH2;
            const int p = z >> 10, k = z & 1023;
            const int o = ((p >> 4) & 3) * 256 + (p >> 6) * 16 + (p & 15);
            Wzb[z] = (__bf16)Wz[(size_t)o * 1024 + k];
        }
    }
    if (idx0 < 1024) {
        const int p = idx0;
        const int o = ((p >> 4) & 3) * 256 + (p >> 6) * 16 + (p & 15);
        bzp[p] = bz[o];
    }
}

// Leaves: 4 rows/block, 4 cols/thread, vectorized bf16x4 stores.
__global__ __launch_bounds__(256) void leaves_kernel(
    const float* __restrict__ data, const float* __restrict__ Wu,
    const float* __restrict__ bu, __bf16* __restrict__ h0)
{
    const int row = blockIdx.x * 4 + (threadIdx.x >> 6);  // b*512 + j
    const int c0 = (threadIdx.x & 63) * 4;
    const int b = row >> 9, j = row & 511;
    const float* d = data + ((size_t)b * NN + 511 + j) * FF;
    float dv[8];
#pragma unroll
    for (int f = 0; f < FF; ++f) dv[f] = d[f];
    bf16x4_t o;
#pragma unroll
    for (int cc = 0; cc < 4; ++cc) {
        const int h = c0 + cc;
        float acc = bu[h];
#pragma unroll
        for (int f = 0; f < FF; ++f) acc += dv[f] * Wu[h * FF + f];
        o[cc] = (__bf16)acc;
    }
    *(bf16x4_t*)&h0[(size_t)row * HH + c0] = o;
}

// hhhu cols 256..1024 = [parent_u, h_l, h_r]; 4 rows/block, bf16x4 copies.
__global__ __launch_bounds__(256) void build_hhu(
    const float* __restrict__ data, const float* __restrict__ Wu,
    const float* __restrict__ bu, const __bf16* __restrict__ hprev,
    __bf16* __restrict__ hhhu, int l, int r0)
{
    const int n = 1 << l;
    const int row = blockIdx.x * 4 + (threadIdx.x >> 6);  // chunk-local row
    const int c0 = (threadIdx.x & 63) * 4;
    const int i = r0 + row;
    const int b = i >> l;
    const int m = i & (n - 1);

    const float* d = data + ((size_t)b * NN + (n - 1) + m) * FF;
    float dv[8];
#pragma unroll
    for (int f = 0; f < FF; ++f) dv[f] = d[f];

    __bf16* rowp = hhhu + (size_t)row * 1024;
    bf16x4_t o;
#pragma unroll
    for (int cc = 0; cc < 4; ++cc) {
        const int h = c0 + cc;
        float acc = bu[h];
#pragma unroll
        for (int f = 0; f < FF; ++f) acc += dv[f] * Wu[h * FF + f];
        o[cc] = (__bf16)acc;
    }
    *(bf16x4_t*)&rowp[256 + c0] = o;
    *(bf16x4_t*)&rowp[512 + c0] =
        *(const bf16x4_t*)&hprev[((size_t)b * (2 * n) + 2 * m) * HH + c0];
    *(bf16x4_t*)&rowp[768 + c0] =
        *(const bf16x4_t*)&hprev[((size_t)b * (2 * n) + 2 * m + 1) * HH + c0];
}

__global__ __launch_bounds__(256) void final_kernel(
    const __bf16* __restrict__ hfin, const float* __restrict__ Wp,
    const float* __restrict__ bp, float* __restrict__ out)
{
    const int b = blockIdx.x;
    const int t = threadIdx.x;
    __shared__ float red[256];
    red[t] = (float)hfin[(size_t)b * HH + t] * Wp[t];
    __syncthreads();
    for (int s = 128; s > 0; s >>= 1) {
        if (t < s) red[t] += red[t + s];
        __syncthreads();
    }
    if (t == 0) out[b] = red[0] + bp[0];
}

extern "C" void kernel_launch(void* const* d_in, const int* in_sizes, int n_in,
                              void* d_out, int out_size, void* d_ws, size_t ws_size,
                              hipStream_t stream)
{
    const float* data = (const float*)d_in[0];
    const float* Wu = (const float*)d_in[1];
    const float* bu = (const float*)d_in[2];
    const float* Wr = (const float*)d_in[3];
    const float* br = (const float*)d_in[4];
    const float* Wh = (const float*)d_in[5];
    const float* bh = (const float*)d_in[6];
    const float* Wz = (const float*)d_in[7];
    const float* bz = (const float*)d_in[8];
    const float* Wp = (const float*)d_in[9];
    const float* bp = (const float*)d_in[10];
    float* out = (float*)d_out;

    const size_t CAP = 32768;  // rows per chunk (multiple of 128)
    char* w = (char*)d_ws;
    __bf16* hA = (__bf16*)w;   w += (size_t)BB * 512 * HH * 2;  // 67.1 MB
    __bf16* hB = (__bf16*)w;   w += (size_t)BB * 256 * HH * 2;  // 33.6 MB
    __bf16* hhhu = (__bf16*)w; w += CAP * 1024 * 2;             // 67.1 MB
    __bf16* rh = (__bf16*)w;   w += CAP * 768 * 2;              // 50.3 MB
    __bf16* Wrb = (__bf16*)w;  w += (size_t)768 * 768 * 2;
    __bf16* Whb = (__bf16*)w;  w += (size_t)256 * 768 * 2;
    __bf16* Wzb = (__bf16*)w;  w += (size_t)1024 * 1024 * 2;
    float* bzp = (float*)w;    w += 1024 * 4;

    convert_weights<<<2048, 256, 0, stream>>>(Wr, Wh, Wz, bz, Wrb, Whb, Wzb, bzp);
    leaves_kernel<<<BB * 512 / 4, 256, 0, stream>>>(data, Wu, bu, hA);

    __bf16* hprev = hA;
    __bf16* hnext = hB;
    for (int l = DEPTH - 1; l >= 0; --l) {
        const size_t M = (size_t)BB << l;
        for (size_t r0 = 0; r0 < M; r0 += CAP) {
            const int R = (int)((M - r0 < CAP) ? (M - r0) : CAP);
            build_hhu<<<R / 4, 256, 0, stream>>>(data, Wu, bu, hprev, hhhu, l, (int)r0);
            dim3 g1(768 / 128, R / 128);
            gemm_mfma<EPI_SIGMUL><<<g1, 256, 0, stream>>>(
                hhhu + 256, 1024, Wrb, br, hhhu + 256, 1024, rh, 768, 768);
            dim3 g2(256 / 128, R / 128);
            gemm_mfma<EPI_RELU><<<g2, 256, 0, stream>>>(
                rh, 768, Whb, bh, nullptr, 0, hhhu, 1024, 768);
            dim3 g3(1024 / 128, R / 128);
            gemm_mfma<EPI_COMBINE><<<g3, 256, 0, stream>>>(
                hhhu, 1024, Wzb, bzp, hhhu, 1024,
                hnext + (size_t)r0 * HH, HH, 1024);
        }
        __bf16* t = hprev; hprev = hnext; hnext = t;
    }
    final_kernel<<<BB, 256, 0, stream>>>(hprev, Wp, bp, out);
}

// Round 4
// 1252.235 us; speedup vs baseline: 6.1198x; 1.1153x over previous
//
#include <hip/hip_runtime.h>
#include <math.h>

#define BB 256
#define NN 1023
#define FF 8
#define HH 256
#define DEPTH 9

enum { EPI_NONE = 0, EPI_SIGMUL = 1, EPI_RELU = 2, EPI_COMBINE = 3 };

typedef __bf16 bf16x8_t __attribute__((ext_vector_type(8)));
typedef __bf16 bf16x4_t __attribute__((ext_vector_type(4)));
typedef float f32x4_t __attribute__((ext_vector_type(4)));

__device__ __forceinline__ void stage16(const void* g, void* l) {
    __builtin_amdgcn_global_load_lds(
        (const __attribute__((address_space(1))) void*)g,
        (__attribute__((address_space(3))) void*)l,
        16, 0, 0);
}

// ---------------- 256x256-tile, 8-wave, BK=64, double-buffered LDS ----------
// "Minimum 2-phase" T3 recipe: STAGE(next) issued BEFORE ds_read+MFMA of
// current tile; single __syncthreads() (vmcnt0+lgkm0+barrier) per K-tile.
template <int EPI>
__global__ __launch_bounds__(512) void gemm256(
    const __bf16* __restrict__ A, int lda,
    const __bf16* __restrict__ W,       // Nc x K row-major
    const float* __restrict__ bias,
    const __bf16* __restrict__ aux, int ldaux,
    void* __restrict__ Cout, int ldc,
    int K)
{
    __shared__ __bf16 lds[2][2][256 * 64];  // [buf][A=0/B=1][256 rows x 64 k]
    const int tid = threadIdx.x;
    const int lane = tid & 63;
    const int w = tid >> 6;          // 0..7
    const int wr = w >> 2, wc = w & 3;

    // bijective XCD swizzle (m204)
    const int nwg = gridDim.x * gridDim.y;
    const int hw = blockIdx.y * gridDim.x + blockIdx.x;
    const int xcd = hw & 7, k0 = hw >> 3;
    const int qq = nwg >> 3, rr = nwg & 7;
    const int wg = (xcd < rr ? xcd * (qq + 1) : rr * (qq + 1) + (xcd - rr) * qq) + k0;
    const int bm0 = (wg / gridDim.x) * 256;
    const int bn0 = (wg % gridDim.x) * 256;

    const int srow = tid >> 3;         // 0..63 (row within a 64-row round)
    const int scol = (tid & 7) * 8;    // bf16 col within 64

    f32x4_t acc[8][4];
#pragma unroll
    for (int i = 0; i < 8; ++i)
#pragma unroll
        for (int j = 0; j < 4; ++j) acc[i][j] = (f32x4_t){0.f, 0.f, 0.f, 0.f};

    const int rA = lane & 15;
    const int klane = (lane >> 4) * 8;
    const int NT = K >> 6;

    // prologue: stage tile 0 into buf 0
#pragma unroll
    for (int p = 0; p < 4; ++p) {
        stage16(A + (size_t)(bm0 + p * 64 + srow) * lda + scol,
                &lds[0][0][p * 4096 + w * 512]);
        stage16(W + (size_t)(bn0 + p * 64 + srow) * K + scol,
                &lds[0][1][p * 4096 + w * 512]);
    }
    __syncthreads();

    for (int kt = 0; kt < NT; ++kt) {
        const int cur = kt & 1;
        if (kt + 1 < NT) {
            const int kk = (kt + 1) << 6;
#pragma unroll
            for (int p = 0; p < 4; ++p) {
                stage16(A + (size_t)(bm0 + p * 64 + srow) * lda + kk + scol,
                        &lds[cur ^ 1][0][p * 4096 + w * 512]);
                stage16(W + (size_t)(bn0 + p * 64 + srow) * K + kk + scol,
                        &lds[cur ^ 1][1][p * 4096 + w * 512]);
            }
        }
        const __bf16* As = lds[cur][0];
        const __bf16* Bs = lds[cur][1];
#pragma unroll
        for (int ks = 0; ks < 2; ++ks) {
            bf16x8_t af[8], bfr[4];
#pragma unroll
            for (int i = 0; i < 8; ++i)
                af[i] = *(const bf16x8_t*)&As[(wr * 128 + i * 16 + rA) * 64 + ks * 32 + klane];
#pragma unroll
            for (int j = 0; j < 4; ++j)
                bfr[j] = *(const bf16x8_t*)&Bs[(wc * 64 + j * 16 + rA) * 64 + ks * 32 + klane];
#pragma unroll
            for (int i = 0; i < 8; ++i)
#pragma unroll
                for (int j = 0; j < 4; ++j)
                    acc[i][j] = __builtin_amdgcn_mfma_f32_16x16x32_bf16(
                        af[i], bfr[j], acc[i][j], 0, 0, 0);
        }
        __syncthreads();
    }

    if (EPI == EPI_COMBINE) {
        const int r = lane & 15;
        const int G = ((bn0 + wc * 64) >> 2) + r;
        float bz4[4];
#pragma unroll
        for (int g = 0; g < 4; ++g) bz4[g] = bias[bn0 + wc * 64 + g * 16 + r];
#pragma unroll
        for (int i = 0; i < 8; ++i) {
#pragma unroll
            for (int reg = 0; reg < 4; ++reg) {
                const int gr = bm0 + wr * 128 + i * 16 + (lane >> 4) * 4 + reg;
                float z0 = acc[i][0][reg] + bz4[0];
                float z1 = acc[i][1][reg] + bz4[1];
                float z2 = acc[i][2][reg] + bz4[2];
                float z3 = acc[i][3][reg] + bz4[3];
                float mx = fmaxf(fmaxf(z0, z1), fmaxf(z2, z3));
                float e0 = __expf(z0 - mx), e1 = __expf(z1 - mx);
                float e2 = __expf(z2 - mx), e3 = __expf(z3 - mx);
                const __bf16* hrow = aux + (size_t)gr * ldaux + G;
                float hv = (e0 * (float)hrow[0] + e1 * (float)hrow[256] +
                            e2 * (float)hrow[512] + e3 * (float)hrow[768]) /
                           (e0 + e1 + e2 + e3);
                ((__bf16*)Cout)[(size_t)gr * ldc + G] = (__bf16)hv;
            }
        }
    } else {
#pragma unroll
        for (int j = 0; j < 4; ++j) {
            const int gc = bn0 + wc * 64 + j * 16 + (lane & 15);
            const float bv = bias[gc];
#pragma unroll
            for (int i = 0; i < 8; ++i) {
#pragma unroll
                for (int reg = 0; reg < 4; ++reg) {
                    const int gr = bm0 + wr * 128 + i * 16 + (lane >> 4) * 4 + reg;
                    float v = acc[i][j][reg] + bv;
                    if (EPI == EPI_SIGMUL) {
                        float s = 1.0f / (1.0f + __expf(-v));
                        v = s * (float)aux[(size_t)gr * ldaux + gc];
                        ((__bf16*)Cout)[(size_t)gr * ldc + gc] = (__bf16)v;
                    } else if (EPI == EPI_RELU) {
                        v = fmaxf(v, 0.0f);
                        ((__bf16*)Cout)[(size_t)gr * ldc + gc] = (__bf16)v;
                    } else {
                        ((float*)Cout)[(size_t)gr * ldc + gc] = v;
                    }
                }
            }
        }
    }
}

// ---------------- 128x128-tile kernel (proven; small levels + Wh) -----------
template <int EPI>
__global__ __launch_bounds__(256) void gemm_mfma(
    const __bf16* __restrict__ A, int lda,
    const __bf16* __restrict__ W,
    const float* __restrict__ bias,
    const __bf16* __restrict__ aux, int ldaux,
    void* __restrict__ Cout, int ldc,
    int K)
{
    __shared__ __bf16 As[128 * 32];
    __shared__ __bf16 Bs[128 * 32];
    const int tid = threadIdx.x;
    const int lane = tid & 63;
    const int w = tid >> 6;
    const int wr = w >> 1, wc = w & 1;

    const int nwg = gridDim.x * gridDim.y;
    const int hw = blockIdx.y * gridDim.x + blockIdx.x;
    const int xcd = hw & 7, k0 = hw >> 3;
    const int qq = nwg >> 3, rr = nwg & 7;
    const int wg = (xcd < rr ? xcd * (qq + 1) : rr * (qq + 1) + (xcd - rr) * qq) + k0;
    const int bm0 = (wg / gridDim.x) * 128;
    const int bn0 = (wg % gridDim.x) * 128;

    const int srow = lane >> 2;
    const int scol = (lane & 3) * 8;

    f32x4_t acc[4][4];
#pragma unroll
    for (int i = 0; i < 4; ++i)
#pragma unroll
        for (int j = 0; j < 4; ++j) acc[i][j] = (f32x4_t){0.f, 0.f, 0.f, 0.f};

    const int rA = lane & 15;
    const int kslot = (lane >> 4) * 8;

    for (int kk = 0; kk < K; kk += 32) {
        stage16(A + (size_t)(bm0 + w * 16 + srow) * lda + kk + scol,
                &As[(w * 16) * 32]);
        stage16(A + (size_t)(bm0 + 64 + w * 16 + srow) * lda + kk + scol,
                &As[(64 + w * 16) * 32]);
        stage16(W + (size_t)(bn0 + w * 16 + srow) * K + kk + scol,
                &Bs[(w * 16) * 32]);
        stage16(W + (size_t)(bn0 + 64 + w * 16 + srow) * K + kk + scol,
                &Bs[(64 + w * 16) * 32]);
        __syncthreads();

        bf16x8_t af[4], bfr[4];
#pragma unroll
        for (int i = 0; i < 4; ++i)
            af[i] = *(const bf16x8_t*)&As[(wr * 64 + i * 16 + rA) * 32 + kslot];
#pragma unroll
        for (int j = 0; j < 4; ++j)
            bfr[j] = *(const bf16x8_t*)&Bs[(wc * 64 + j * 16 + rA) * 32 + kslot];
#pragma unroll
        for (int i = 0; i < 4; ++i)
#pragma unroll
            for (int j = 0; j < 4; ++j)
                acc[i][j] = __builtin_amdgcn_mfma_f32_16x16x32_bf16(
                    af[i], bfr[j], acc[i][j], 0, 0, 0);
        __syncthreads();
    }

    if (EPI == EPI_COMBINE) {
        const int r = lane & 15;
        const int G = ((bn0 + wc * 64) >> 2) + r;
        float bz4[4];
#pragma unroll
        for (int g = 0; g < 4; ++g) bz4[g] = bias[bn0 + wc * 64 + g * 16 + r];
#pragma unroll
        for (int i = 0; i < 4; ++i) {
#pragma unroll
            for (int reg = 0; reg < 4; ++reg) {
                const int gr = bm0 + wr * 64 + i * 16 + (lane >> 4) * 4 + reg;
                float z0 = acc[i][0][reg] + bz4[0];
                float z1 = acc[i][1][reg] + bz4[1];
                float z2 = acc[i][2][reg] + bz4[2];
                float z3 = acc[i][3][reg] + bz4[3];
                float mx = fmaxf(fmaxf(z0, z1), fmaxf(z2, z3));
                float e0 = __expf(z0 - mx), e1 = __expf(z1 - mx);
                float e2 = __expf(z2 - mx), e3 = __expf(z3 - mx);
                const __bf16* hrow = aux + (size_t)gr * ldaux + G;
                float hv = (e0 * (float)hrow[0] + e1 * (float)hrow[256] +
                            e2 * (float)hrow[512] + e3 * (float)hrow[768]) /
                           (e0 + e1 + e2 + e3);
                ((__bf16*)Cout)[(size_t)gr * ldc + G] = (__bf16)hv;
            }
        }
    } else {
#pragma unroll
        for (int j = 0; j < 4; ++j) {
            const int gc = bn0 + wc * 64 + j * 16 + (lane & 15);
            const float bv = bias[gc];
#pragma unroll
            for (int i = 0; i < 4; ++i) {
#pragma unroll
                for (int reg = 0; reg < 4; ++reg) {
                    const int gr = bm0 + wr * 64 + i * 16 + (lane >> 4) * 4 + reg;
                    float v = acc[i][j][reg] + bv;
                    if (EPI == EPI_SIGMUL) {
                        float s = 1.0f / (1.0f + __expf(-v));
                        v = s * (float)aux[(size_t)gr * ldaux + gc];
                        ((__bf16*)Cout)[(size_t)gr * ldc + gc] = (__bf16)v;
                    } else if (EPI == EPI_RELU) {
                        v = fmaxf(v, 0.0f);
                        ((__bf16*)Cout)[(size_t)gr * ldc + gc] = (__bf16)v;
                    } else {
                        ((float*)Cout)[(size_t)gr * ldc + gc] = v;
                    }
                }
            }
        }
    }
}

// Wr/Wh -> bf16; Wz -> bf16 with softmax-group row permutation.
__global__ __launch_bounds__(256) void convert_weights(
    const float* __restrict__ Wr, const float* __restrict__ Wh,
    const float* __restrict__ Wz, const float* __restrict__ bz,
    __bf16* __restrict__ Wrb, __bf16* __restrict__ Whb,
    __bf16* __restrict__ Wzb, float* __restrict__ bzp)
{
    const int NR = 768 * 768, NH2 = 256 * 768, NZ = 1024 * 1024;
    const int idx0 = blockIdx.x * 256 + threadIdx.x;
    for (int i = idx0; i < NR + NH2 + NZ; i += gridDim.x * 256) {
        if (i < NR) Wrb[i] = (__bf16)Wr[i];
        else if (i < NR + NH2) Whb[i - NR] = (__bf16)Wh[i - NR];
        else {
            const int z = i - NR - NH2;
            const int p = z >> 10, k = z & 1023;
            const int o = ((p >> 4) & 3) * 256 + (p >> 6) * 16 + (p & 15);
            Wzb[z] = (__bf16)Wz[(size_t)o * 1024 + k];
        }
    }
    if (idx0 < 1024) {
        const int p = idx0;
        const int o = ((p >> 4) & 3) * 256 + (p >> 6) * 16 + (p & 15);
        bzp[p] = bz[o];
    }
}

// hhhu cols 256..1024 = [parent_u, h_l, h_r]; 8 rows/block, 8 cols/thread.
// For l==8 the children are LEAVES: compute their u directly from data
// (replaces the old leaves_kernel 67MB write + 67MB read round-trip).
__global__ __launch_bounds__(256) void build_hhu(
    const float* __restrict__ data, const float* __restrict__ Wu,
    const float* __restrict__ bu, const __bf16* __restrict__ hprev,
    __bf16* __restrict__ hhhu, int l, int r0)
{
    const int n = 1 << l;
    const int row = blockIdx.x * 8 + (threadIdx.x >> 5);
    const int c0 = (threadIdx.x & 31) * 8;
    const int i = r0 + row;
    const int b = i >> l;
    const int m = i & (n - 1);

    float wv[8][8];
#pragma unroll
    for (int cc = 0; cc < 8; ++cc) {
        float4 w0 = *(const float4*)&Wu[(c0 + cc) * 8];
        float4 w1 = *(const float4*)&Wu[(c0 + cc) * 8 + 4];
        wv[cc][0] = w0.x; wv[cc][1] = w0.y; wv[cc][2] = w0.z; wv[cc][3] = w0.w;
        wv[cc][4] = w1.x; wv[cc][5] = w1.y; wv[cc][6] = w1.z; wv[cc][7] = w1.w;
    }
    float buv[8];
#pragma unroll
    for (int cc = 0; cc < 8; ++cc) buv[cc] = bu[c0 + cc];

    __bf16* rowp = hhhu + (size_t)row * 1024;

    // parent u
    {
        const float* dp = data + ((size_t)b * NN + (n - 1) + m) * FF;
        float4 d0 = *(const float4*)dp, d1 = *(const float4*)(dp + 4);
        float dv[8] = {d0.x, d0.y, d0.z, d0.w, d1.x, d1.y, d1.z, d1.w};
        bf16x8_t o;
#pragma unroll
        for (int cc = 0; cc < 8; ++cc) {
            float acc = buv[cc];
#pragma unroll
            for (int f = 0; f < 8; ++f) acc += dv[f] * wv[cc][f];
            o[cc] = (__bf16)acc;
        }
        *(bf16x8_t*)&rowp[256 + c0] = o;
    }

    if (l == 8) {
        const float* dl = data + ((size_t)b * NN + 511 + 2 * m) * FF;
#pragma unroll
        for (int side = 0; side < 2; ++side) {
            const float* dp = dl + side * FF;
            float4 d0 = *(const float4*)dp, d1 = *(const float4*)(dp + 4);
            float dv[8] = {d0.x, d0.y, d0.z, d0.w, d1.x, d1.y, d1.z, d1.w};
            bf16x8_t o;
#pragma unroll
            for (int cc = 0; cc < 8; ++cc) {
                float acc = buv[cc];
#pragma unroll
                for (int f = 0; f < 8; ++f) acc += dv[f] * wv[cc][f];
                o[cc] = (__bf16)acc;
            }
            *(bf16x8_t*)&rowp[512 + side * 256 + c0] = o;
        }
    } else {
        *(bf16x8_t*)&rowp[512 + c0] =
            *(const bf16x8_t*)&hprev[((size_t)b * (2 * n) + 2 * m) * HH + c0];
        *(bf16x8_t*)&rowp[768 + c0] =
            *(const bf16x8_t*)&hprev[((size_t)b * (2 * n) + 2 * m + 1) * HH + c0];
    }
}

__global__ __launch_bounds__(256) void final_kernel(
    const __bf16* __restrict__ hfin, const float* __restrict__ Wp,
    const float* __restrict__ bp, float* __restrict__ out)
{
    const int b = blockIdx.x;
    const int t = threadIdx.x;
    __shared__ float red[256];
    red[t] = (float)hfin[(size_t)b * HH + t] * Wp[t];
    __syncthreads();
    for (int s = 128; s > 0; s >>= 1) {
        if (t < s) red[t] += red[t + s];
        __syncthreads();
    }
    if (t == 0) out[b] = red[0] + bp[0];
}

extern "C" void kernel_launch(void* const* d_in, const int* in_sizes, int n_in,
                              void* d_out, int out_size, void* d_ws, size_t ws_size,
                              hipStream_t stream)
{
    const float* data = (const float*)d_in[0];
    const float* Wu = (const float*)d_in[1];
    const float* bu = (const float*)d_in[2];
    const float* Wr = (const float*)d_in[3];
    const float* br = (const float*)d_in[4];
    const float* Wh = (const float*)d_in[5];
    const float* bh = (const float*)d_in[6];
    const float* Wz = (const float*)d_in[7];
    const float* bz = (const float*)d_in[8];
    const float* Wp = (const float*)d_in[9];
    const float* bp = (const float*)d_in[10];
    float* out = (float*)d_out;

    const size_t CAP = 32768;
    char* w = (char*)d_ws;
    __bf16* hA = (__bf16*)w;   w += (size_t)65536 * HH * 2;   // 33.6 MB
    __bf16* hB = (__bf16*)w;   w += (size_t)32768 * HH * 2;   // 16.8 MB
    __bf16* hhhu = (__bf16*)w; w += CAP * 1024 * 2;           // 67.1 MB
    __bf16* rh = (__bf16*)w;   w += CAP * 768 * 2;            // 50.3 MB
    __bf16* Wrb = (__bf16*)w;  w += (size_t)768 * 768 * 2;
    __bf16* Whb = (__bf16*)w;  w += (size_t)256 * 768 * 2;
    __bf16* Wzb = (__bf16*)w;  w += (size_t)1024 * 1024 * 2;
    float* bzp = (float*)w;    w += 1024 * 4;

    convert_weights<<<2048, 256, 0, stream>>>(Wr, Wh, Wz, bz, Wrb, Whb, Wzb, bzp);

    for (int l = DEPTH - 1; l >= 0; --l) {
        const size_t M = (size_t)BB << l;
        __bf16* dst = ((DEPTH - 1 - l) & 1) ? hB : hA;
        const __bf16* src = ((DEPTH - 1 - l) & 1) ? hA : hB;  // unused at l=8
        for (size_t r0 = 0; r0 < M; r0 += CAP) {
            const int R = (int)((M - r0 < CAP) ? (M - r0) : CAP);
            build_hhu<<<R / 8, 256, 0, stream>>>(data, Wu, bu, src, hhhu, l, (int)r0);
            if (R >= 32768) {
                gemm256<EPI_SIGMUL><<<dim3(3, R / 256), 512, 0, stream>>>(
                    hhhu + 256, 1024, Wrb, br, hhhu + 256, 1024, rh, 768, 768);
            } else {
                gemm_mfma<EPI_SIGMUL><<<dim3(6, R / 128), 256, 0, stream>>>(
                    hhhu + 256, 1024, Wrb, br, hhhu + 256, 1024, rh, 768, 768);
            }
            gemm_mfma<EPI_RELU><<<dim3(2, R / 128), 256, 0, stream>>>(
                rh, 768, Whb, bh, nullptr, 0, hhhu, 1024, 768);
            if (R >= 16384) {
                gemm256<EPI_COMBINE><<<dim3(4, R / 256), 512, 0, stream>>>(
                    hhhu, 1024, Wzb, bzp, hhhu, 1024,
                    dst + (size_t)r0 * HH, HH, 1024);
            } else {
                gemm_mfma<EPI_COMBINE><<<dim3(8, R / 128), 256, 0, stream>>>(
                    hhhu, 1024, Wzb, bzp, hhhu, 1024,
                    dst + (size_t)r0 * HH, HH, 1024);
            }
        }
    }
    final_kernel<<<BB, 256, 0, stream>>>(hA, Wp, bp, out);
}

// Round 5
// 1239.836 us; speedup vs baseline: 6.1810x; 1.0100x over previous
//
#include <hip/hip_runtime.h>
#include <math.h>

#define BB 256
#define NN 1023
#define FF 8
#define HH 256
#define DEPTH 9

enum { EPI_NONE = 0, EPI_SIGMUL = 1, EPI_RELU = 2, EPI_COMBINE = 3 };

typedef __bf16 bf16x8_t __attribute__((ext_vector_type(8)));
typedef float f32x4_t __attribute__((ext_vector_type(4)));

__device__ __forceinline__ void stage16(const void* g, void* l) {
    __builtin_amdgcn_global_load_lds(
        (const __attribute__((address_space(1))) void*)g,
        (__attribute__((address_space(3))) void*)l,
        16, 0, 0);
}

// ============ 256x256 tile, BK=64, 8 waves, counted-vmcnt pipeline ==========
// Double-buffered LDS; stage(t+2) issued into buf p AFTER a barrier proving
// all waves finished ds_reading tile t from buf p; end-of-iter wait is
// vmcnt(8) (t+2's loads stay in flight across the barrier), never vmcnt(0).
// T2 XOR-swizzle: linear LDS dest (global_load_lds) + inverse-swizzled global
// source column + same XOR on ds_read addresses (rule #21 both-sides).
template <int EPI>
__global__ __launch_bounds__(512, 2) void gemm256p(
    const __bf16* __restrict__ A, int lda,
    const __bf16* __restrict__ W,       // Nc x K row-major
    const float* __restrict__ bias,
    const __bf16* __restrict__ aux, int ldaux,
    void* __restrict__ Cout, int ldc,
    int K)
{
    __shared__ __bf16 lds[2][2][256 * 64];  // [buf][A=0/B=1], 128 KiB total
    const int tid = threadIdx.x;
    const int lane = tid & 63;
    const int w = tid >> 6;            // 0..7
    const int wr = w >> 2, wc = w & 3; // 2M x 4N waves; per-wave C = 128x64

    // bijective XCD swizzle (m204)
    const int nwg = gridDim.x * gridDim.y;
    const int hw = blockIdx.y * gridDim.x + blockIdx.x;
    const int xcd = hw & 7, k0 = hw >> 3;
    const int qq = nwg >> 3, rr = nwg & 7;
    const int wg = (xcd < rr ? xcd * (qq + 1) : rr * (qq + 1) + (xcd - rr) * qq) + k0;
    const int bm0 = (wg / gridDim.x) * 256;
    const int bn0 = (wg % gridDim.x) * 256;

    // staging geometry: 512 thr x 16B = 8KB = 64 rows/round; 4 rounds per op.
    const int srow = tid >> 3;                              // 0..63
    const int scolz = ((tid & 7) ^ ((tid >> 3) & 7)) * 8;   // inv-swizzled col

    f32x4_t acc[8][4];
#pragma unroll
    for (int i = 0; i < 8; ++i)
#pragma unroll
        for (int j = 0; j < 4; ++j) acc[i][j] = (f32x4_t){0.f, 0.f, 0.f, 0.f};

    const int rA = lane & 15;
    const int klane = (lane >> 4) * 8;
    const int rxor = (lane & 7) * 8;   // (row&7)*8 for all frag rows
    const int NT = K >> 6;

#define STAGE_T(t, buf)                                                        \
    do {                                                                       \
        const int kk_ = (t) << 6;                                              \
        _Pragma("unroll")                                                      \
        for (int rnd = 0; rnd < 4; ++rnd) {                                    \
            stage16(A + (size_t)(bm0 + rnd * 64 + srow) * lda + kk_ + scolz,   \
                    &lds[buf][0][rnd * 4096 + w * 512]);                       \
            stage16(W + (size_t)(bn0 + rnd * 64 + srow) * K + kk_ + scolz,     \
                    &lds[buf][1][rnd * 4096 + w * 512]);                       \
        }                                                                      \
    } while (0)

#define LDA_F(As_, i, ks) \
    (*(const bf16x8_t*)&(As_)[(wr * 128 + (i) * 16 + rA) * 64 + (((ks) * 32 + klane) ^ rxor)])
#define LDB_F(Bs_, j, ks) \
    (*(const bf16x8_t*)&(Bs_)[(wc * 64 + (j) * 16 + rA) * 64 + (((ks) * 32 + klane) ^ rxor)])

    // prologue: stage tiles 0 and 1; wait tile 0 landed (8 newest in flight).
    STAGE_T(0, 0);
    STAGE_T(1, 1);
    asm volatile("s_waitcnt vmcnt(8)" ::: "memory");
    __builtin_amdgcn_sched_barrier(0);
    __builtin_amdgcn_s_barrier();
    __builtin_amdgcn_sched_barrier(0);

    for (int t = 0; t < NT; ++t) {
        const int p = t & 1;
        const __bf16* As = lds[p][0];
        const __bf16* Bs = lds[p][1];

        bf16x8_t b0[4], b1[4], alo[4], ahi[4];
        // ks = 0
#pragma unroll
        for (int j = 0; j < 4; ++j) b0[j] = LDB_F(Bs, j, 0);
#pragma unroll
        for (int i = 0; i < 4; ++i) alo[i] = LDA_F(As, i, 0);
#pragma unroll
        for (int i = 0; i < 4; ++i)
#pragma unroll
            for (int j = 0; j < 4; ++j)
                acc[i][j] = __builtin_amdgcn_mfma_f32_16x16x32_bf16(
                    alo[i], b0[j], acc[i][j], 0, 0, 0);
#pragma unroll
        for (int i = 0; i < 4; ++i) ahi[i] = LDA_F(As, 4 + i, 0);
#pragma unroll
        for (int i = 0; i < 4; ++i)
#pragma unroll
            for (int j = 0; j < 4; ++j)
                acc[4 + i][j] = __builtin_amdgcn_mfma_f32_16x16x32_bf16(
                    ahi[i], b0[j], acc[4 + i][j], 0, 0, 0);
        // ks = 1
#pragma unroll
        for (int j = 0; j < 4; ++j) b1[j] = LDB_F(Bs, j, 1);
#pragma unroll
        for (int i = 0; i < 4; ++i) alo[i] = LDA_F(As, i, 1);
#pragma unroll
        for (int i = 0; i < 4; ++i) ahi[i] = LDA_F(As, 4 + i, 1);
#pragma unroll
        for (int i = 0; i < 4; ++i)
#pragma unroll
            for (int j = 0; j < 4; ++j)
                acc[i][j] = __builtin_amdgcn_mfma_f32_16x16x32_bf16(
                    alo[i], b1[j], acc[i][j], 0, 0, 0);

        // all this wave's ds_reads of buf p are now issued; drain them, then
        // barrier: after it, no wave will read buf p for tile t again.
        asm volatile("s_waitcnt lgkmcnt(0)" ::: "memory");
        __builtin_amdgcn_sched_barrier(0);
        __builtin_amdgcn_s_barrier();
        __builtin_amdgcn_sched_barrier(0);

        if (t + 2 < NT) STAGE_T(t + 2, p);   // overwrite buf p (safe now)

        __builtin_amdgcn_s_setprio(1);
#pragma unroll
        for (int i = 0; i < 4; ++i)
#pragma unroll
            for (int j = 0; j < 4; ++j)
                acc[4 + i][j] = __builtin_amdgcn_mfma_f32_16x16x32_bf16(
                    ahi[i], b1[j], acc[4 + i][j], 0, 0, 0);
        __builtin_amdgcn_s_setprio(0);

        if (t + 1 < NT) {
            // ensure tile t+1 landed; keep t+2's 8 loads in flight.
            if (t + 2 < NT) {
                asm volatile("s_waitcnt vmcnt(8)" ::: "memory");
            } else {
                asm volatile("s_waitcnt vmcnt(0)" ::: "memory");
            }
            __builtin_amdgcn_sched_barrier(0);
            __builtin_amdgcn_s_barrier();
            __builtin_amdgcn_sched_barrier(0);
        }
    }
#undef STAGE_T
#undef LDA_F
#undef LDB_F

    if (EPI == EPI_COMBINE) {
        const int r = lane & 15;
        const int G = ((bn0 + wc * 64) >> 2) + r;
        float bz4[4];
#pragma unroll
        for (int g = 0; g < 4; ++g) bz4[g] = bias[bn0 + wc * 64 + g * 16 + r];
#pragma unroll
        for (int i = 0; i < 8; ++i) {
#pragma unroll
            for (int reg = 0; reg < 4; ++reg) {
                const int gr = bm0 + wr * 128 + i * 16 + (lane >> 4) * 4 + reg;
                float z0 = acc[i][0][reg] + bz4[0];
                float z1 = acc[i][1][reg] + bz4[1];
                float z2 = acc[i][2][reg] + bz4[2];
                float z3 = acc[i][3][reg] + bz4[3];
                float mx = fmaxf(fmaxf(z0, z1), fmaxf(z2, z3));
                float e0 = __expf(z0 - mx), e1 = __expf(z1 - mx);
                float e2 = __expf(z2 - mx), e3 = __expf(z3 - mx);
                const __bf16* hrow = aux + (size_t)gr * ldaux + G;
                float hv = (e0 * (float)hrow[0] + e1 * (float)hrow[256] +
                            e2 * (float)hrow[512] + e3 * (float)hrow[768]) /
                           (e0 + e1 + e2 + e3);
                ((__bf16*)Cout)[(size_t)gr * ldc + G] = (__bf16)hv;
            }
        }
    } else {
#pragma unroll
        for (int j = 0; j < 4; ++j) {
            const int gc = bn0 + wc * 64 + j * 16 + (lane & 15);
            const float bv = bias[gc];
#pragma unroll
            for (int i = 0; i < 8; ++i) {
#pragma unroll
                for (int reg = 0; reg < 4; ++reg) {
                    const int gr = bm0 + wr * 128 + i * 16 + (lane >> 4) * 4 + reg;
                    float v = acc[i][j][reg] + bv;
                    if (EPI == EPI_SIGMUL) {
                        float s = 1.0f / (1.0f + __expf(-v));
                        v = s * (float)aux[(size_t)gr * ldaux + gc];
                        ((__bf16*)Cout)[(size_t)gr * ldc + gc] = (__bf16)v;
                    } else if (EPI == EPI_RELU) {
                        v = fmaxf(v, 0.0f);
                        ((__bf16*)Cout)[(size_t)gr * ldc + gc] = (__bf16)v;
                    } else {
                        ((float*)Cout)[(size_t)gr * ldc + gc] = v;
                    }
                }
            }
        }
    }
}

// ---------------- 128x128-tile kernel (proven; Wh + small levels) -----------
template <int EPI>
__global__ __launch_bounds__(256) void gemm_mfma(
    const __bf16* __restrict__ A, int lda,
    const __bf16* __restrict__ W,
    const float* __restrict__ bias,
    const __bf16* __restrict__ aux, int ldaux,
    void* __restrict__ Cout, int ldc,
    int K)
{
    __shared__ __bf16 As[128 * 32];
    __shared__ __bf16 Bs[128 * 32];
    const int tid = threadIdx.x;
    const int lane = tid & 63;
    const int w = tid >> 6;
    const int wr = w >> 1, wc = w & 1;

    const int nwg = gridDim.x * gridDim.y;
    const int hw = blockIdx.y * gridDim.x + blockIdx.x;
    const int xcd = hw & 7, k0 = hw >> 3;
    const int qq = nwg >> 3, rr = nwg & 7;
    const int wg = (xcd < rr ? xcd * (qq + 1) : rr * (qq + 1) + (xcd - rr) * qq) + k0;
    const int bm0 = (wg / gridDim.x) * 128;
    const int bn0 = (wg % gridDim.x) * 128;

    const int srow = lane >> 2;
    const int scol = (lane & 3) * 8;

    f32x4_t acc[4][4];
#pragma unroll
    for (int i = 0; i < 4; ++i)
#pragma unroll
        for (int j = 0; j < 4; ++j) acc[i][j] = (f32x4_t){0.f, 0.f, 0.f, 0.f};

    const int rA = lane & 15;
    const int kslot = (lane >> 4) * 8;

    for (int kk = 0; kk < K; kk += 32) {
        stage16(A + (size_t)(bm0 + w * 16 + srow) * lda + kk + scol,
                &As[(w * 16) * 32]);
        stage16(A + (size_t)(bm0 + 64 + w * 16 + srow) * lda + kk + scol,
                &As[(64 + w * 16) * 32]);
        stage16(W + (size_t)(bn0 + w * 16 + srow) * K + kk + scol,
                &Bs[(w * 16) * 32]);
        stage16(W + (size_t)(bn0 + 64 + w * 16 + srow) * K + kk + scol,
                &Bs[(64 + w * 16) * 32]);
        __syncthreads();

        bf16x8_t af[4], bfr[4];
#pragma unroll
        for (int i = 0; i < 4; ++i)
            af[i] = *(const bf16x8_t*)&As[(wr * 64 + i * 16 + rA) * 32 + kslot];
#pragma unroll
        for (int j = 0; j < 4; ++j)
            bfr[j] = *(const bf16x8_t*)&Bs[(wc * 64 + j * 16 + rA) * 32 + kslot];
#pragma unroll
        for (int i = 0; i < 4; ++i)
#pragma unroll
            for (int j = 0; j < 4; ++j)
                acc[i][j] = __builtin_amdgcn_mfma_f32_16x16x32_bf16(
                    af[i], bfr[j], acc[i][j], 0, 0, 0);
        __syncthreads();
    }

    if (EPI == EPI_COMBINE) {
        const int r = lane & 15;
        const int G = ((bn0 + wc * 64) >> 2) + r;
        float bz4[4];
#pragma unroll
        for (int g = 0; g < 4; ++g) bz4[g] = bias[bn0 + wc * 64 + g * 16 + r];
#pragma unroll
        for (int i = 0; i < 4; ++i) {
#pragma unroll
            for (int reg = 0; reg < 4; ++reg) {
                const int gr = bm0 + wr * 64 + i * 16 + (lane >> 4) * 4 + reg;
                float z0 = acc[i][0][reg] + bz4[0];
                float z1 = acc[i][1][reg] + bz4[1];
                float z2 = acc[i][2][reg] + bz4[2];
                float z3 = acc[i][3][reg] + bz4[3];
                float mx = fmaxf(fmaxf(z0, z1), fmaxf(z2, z3));
                float e0 = __expf(z0 - mx), e1 = __expf(z1 - mx);
                float e2 = __expf(z2 - mx), e3 = __expf(z3 - mx);
                const __bf16* hrow = aux + (size_t)gr * ldaux + G;
                float hv = (e0 * (float)hrow[0] + e1 * (float)hrow[256] +
                            e2 * (float)hrow[512] + e3 * (float)hrow[768]) /
                           (e0 + e1 + e2 + e3);
                ((__bf16*)Cout)[(size_t)gr * ldc + G] = (__bf16)hv;
            }
        }
    } else {
#pragma unroll
        for (int j = 0; j < 4; ++j) {
            const int gc = bn0 + wc * 64 + j * 16 + (lane & 15);
            const float bv = bias[gc];
#pragma unroll
            for (int i = 0; i < 4; ++i) {
#pragma unroll
                for (int reg = 0; reg < 4; ++reg) {
                    const int gr = bm0 + wr * 64 + i * 16 + (lane >> 4) * 4 + reg;
                    float v = acc[i][j][reg] + bv;
                    if (EPI == EPI_SIGMUL) {
                        float s = 1.0f / (1.0f + __expf(-v));
                        v = s * (float)aux[(size_t)gr * ldaux + gc];
                        ((__bf16*)Cout)[(size_t)gr * ldc + gc] = (__bf16)v;
                    } else if (EPI == EPI_RELU) {
                        v = fmaxf(v, 0.0f);
                        ((__bf16*)Cout)[(size_t)gr * ldc + gc] = (__bf16)v;
                    } else {
                        ((float*)Cout)[(size_t)gr * ldc + gc] = v;
                    }
                }
            }
        }
    }
}

// Wr/Wh -> bf16; Wz -> bf16 with softmax-group row permutation.
__global__ __launch_bounds__(256) void convert_weights(
    const float* __restrict__ Wr, const float* __restrict__ Wh,
    const float* __restrict__ Wz, const float* __restrict__ bz,
    __bf16* __restrict__ Wrb, __bf16* __restrict__ Whb,
    __bf16* __restrict__ Wzb, float* __restrict__ bzp)
{
    const int NR = 768 * 768, NH2 = 256 * 768, NZ = 1024 * 1024;
    const int idx0 = blockIdx.x * 256 + threadIdx.x;
    for (int i = idx0; i < NR + NH2 + NZ; i += gridDim.x * 256) {
        if (i < NR) Wrb[i] = (__bf16)Wr[i];
        else if (i < NR + NH2) Whb[i - NR] = (__bf16)Wh[i - NR];
        else {
            const int z = i - NR - NH2;
            const int p = z >> 10, k = z & 1023;
            const int o = ((p >> 4) & 3) * 256 + (p >> 6) * 16 + (p & 15);
            Wzb[z] = (__bf16)Wz[(size_t)o * 1024 + k];
        }
    }
    if (idx0 < 1024) {
        const int p = idx0;
        const int o = ((p >> 4) & 3) * 256 + (p >> 6) * 16 + (p & 15);
        bzp[p] = bz[o];
    }
}

// hhhu cols 256..1024 = [parent_u, h_l, h_r]; 8 rows/block, 8 cols/thread.
__global__ __launch_bounds__(256) void build_hhu(
    const float* __restrict__ data, const float* __restrict__ Wu,
    const float* __restrict__ bu, const __bf16* __restrict__ hprev,
    __bf16* __restrict__ hhhu, int l, int r0)
{
    const int n = 1 << l;
    const int row = blockIdx.x * 8 + (threadIdx.x >> 5);
    const int c0 = (threadIdx.x & 31) * 8;
    const int i = r0 + row;
    const int b = i >> l;
    const int m = i & (n - 1);

    float wv[8][8];
#pragma unroll
    for (int cc = 0; cc < 8; ++cc) {
        float4 w0 = *(const float4*)&Wu[(c0 + cc) * 8];
        float4 w1 = *(const float4*)&Wu[(c0 + cc) * 8 + 4];
        wv[cc][0] = w0.x; wv[cc][1] = w0.y; wv[cc][2] = w0.z; wv[cc][3] = w0.w;
        wv[cc][4] = w1.x; wv[cc][5] = w1.y; wv[cc][6] = w1.z; wv[cc][7] = w1.w;
    }
    float buv[8];
#pragma unroll
    for (int cc = 0; cc < 8; ++cc) buv[cc] = bu[c0 + cc];

    __bf16* rowp = hhhu + (size_t)row * 1024;

    {
        const float* dp = data + ((size_t)b * NN + (n - 1) + m) * FF;
        float4 d0 = *(const float4*)dp, d1 = *(const float4*)(dp + 4);
        float dv[8] = {d0.x, d0.y, d0.z, d0.w, d1.x, d1.y, d1.z, d1.w};
        bf16x8_t o;
#pragma unroll
        for (int cc = 0; cc < 8; ++cc) {
            float acc = buv[cc];
#pragma unroll
            for (int f = 0; f < 8; ++f) acc += dv[f] * wv[cc][f];
            o[cc] = (__bf16)acc;
        }
        *(bf16x8_t*)&rowp[256 + c0] = o;
    }

    if (l == 8) {
        const float* dl = data + ((size_t)b * NN + 511 + 2 * m) * FF;
#pragma unroll
        for (int side = 0; side < 2; ++side) {
            const float* dp = dl + side * FF;
            float4 d0 = *(const float4*)dp, d1 = *(const float4*)(dp + 4);
            float dv[8] = {d0.x, d0.y, d0.z, d0.w, d1.x, d1.y, d1.z, d1.w};
            bf16x8_t o;
#pragma unroll
            for (int cc = 0; cc < 8; ++cc) {
                float acc = buv[cc];
#pragma unroll
                for (int f = 0; f < 8; ++f) acc += dv[f] * wv[cc][f];
                o[cc] = (__bf16)acc;
            }
            *(bf16x8_t*)&rowp[512 + side * 256 + c0] = o;
        }
    } else {
        *(bf16x8_t*)&rowp[512 + c0] =
            *(const bf16x8_t*)&hprev[((size_t)b * (2 * n) + 2 * m) * HH + c0];
        *(bf16x8_t*)&rowp[768 + c0] =
            *(const bf16x8_t*)&hprev[((size_t)b * (2 * n) + 2 * m + 1) * HH + c0];
    }
}

__global__ __launch_bounds__(256) void final_kernel(
    const __bf16* __restrict__ hfin, const float* __restrict__ Wp,
    const float* __restrict__ bp, float* __restrict__ out)
{
    const int b = blockIdx.x;
    const int t = threadIdx.x;
    __shared__ float red[256];
    red[t] = (float)hfin[(size_t)b * HH + t] * Wp[t];
    __syncthreads();
    for (int s = 128; s > 0; s >>= 1) {
        if (t < s) red[t] += red[t + s];
        __syncthreads();
    }
    if (t == 0) out[b] = red[0] + bp[0];
}

extern "C" void kernel_launch(void* const* d_in, const int* in_sizes, int n_in,
                              void* d_out, int out_size, void* d_ws, size_t ws_size,
                              hipStream_t stream)
{
    const float* data = (const float*)d_in[0];
    const float* Wu = (const float*)d_in[1];
    const float* bu = (const float*)d_in[2];
    const float* Wr = (const float*)d_in[3];
    const float* br = (const float*)d_in[4];
    const float* Wh = (const float*)d_in[5];
    const float* bh = (const float*)d_in[6];
    const float* Wz = (const float*)d_in[7];
    const float* bz = (const float*)d_in[8];
    const float* Wp = (const float*)d_in[9];
    const float* bp = (const float*)d_in[10];
    float* out = (float*)d_out;

    const size_t CAP = 32768;
    char* w = (char*)d_ws;
    __bf16* hA = (__bf16*)w;   w += (size_t)65536 * HH * 2;
    __bf16* hB = (__bf16*)w;   w += (size_t)32768 * HH * 2;
    __bf16* hhhu = (__bf16*)w; w += CAP * 1024 * 2;
    __bf16* rh = (__bf16*)w;   w += CAP * 768 * 2;
    __bf16* Wrb = (__bf16*)w;  w += (size_t)768 * 768 * 2;
    __bf16* Whb = (__bf16*)w;  w += (size_t)256 * 768 * 2;
    __bf16* Wzb = (__bf16*)w;  w += (size_t)1024 * 1024 * 2;
    float* bzp = (float*)w;    w += 1024 * 4;

    convert_weights<<<2048, 256, 0, stream>>>(Wr, Wh, Wz, bz, Wrb, Whb, Wzb, bzp);

    for (int l = DEPTH - 1; l >= 0; --l) {
        const size_t M = (size_t)BB << l;
        __bf16* dst = ((DEPTH - 1 - l) & 1) ? hB : hA;
        const __bf16* src = ((DEPTH - 1 - l) & 1) ? hA : hB;  // unused at l=8
        for (size_t r0 = 0; r0 < M; r0 += CAP) {
            const int R = (int)((M - r0 < CAP) ? (M - r0) : CAP);
            build_hhu<<<R / 8, 256, 0, stream>>>(data, Wu, bu, src, hhhu, l, (int)r0);
            if (R >= 2048) {
                gemm256p<EPI_SIGMUL><<<dim3(3, R / 256), 512, 0, stream>>>(
                    hhhu + 256, 1024, Wrb, br, hhhu + 256, 1024, rh, 768, 768);
            } else {
                gemm_mfma<EPI_SIGMUL><<<dim3(6, R / 128), 256, 0, stream>>>(
                    hhhu + 256, 1024, Wrb, br, hhhu + 256, 1024, rh, 768, 768);
            }
            gemm_mfma<EPI_RELU><<<dim3(2, R / 128), 256, 0, stream>>>(
                rh, 768, Whb, bh, nullptr, 0, hhhu, 1024, 768);
            if (R >= 2048) {
                gemm256p<EPI_COMBINE><<<dim3(4, R / 256), 512, 0, stream>>>(
                    hhhu, 1024, Wzb, bzp, hhhu, 1024,
                    dst + (size_t)r0 * HH, HH, 1024);
            } else {
                gemm_mfma<EPI_COMBINE><<<dim3(8, R / 128), 256, 0, stream>>>(
                    hhhu, 1024, Wzb, bzp, hhhu, 1024,
                    dst + (size_t)r0 * HH, HH, 1024);
            }
        }
    }
    final_kernel<<<BB, 256, 0, stream>>>(hA, Wp, bp, out);
}